// Round 9
// baseline (540.409 us; speedup 1.0000x reference)
//
#include <hip/hip_runtime.h>
#include <hip/hip_bf16.h>

#define NNODES 50000
#define NREL   16
#define NEDGE  400000
#define BN_EPS 1e-5f
#define M_REAL NNODES
#define MT64   782             /* ceil(50000/64) */
#define RPX64  98              /* ceil(782/8) row-blocks per XCD */
#define SCAN_B 512
#define SCAN_NB ((NNODES + SCAN_B - 1) / SCAN_B)   /* 98 */

typedef __attribute__((ext_vector_type(8))) short short8;
typedef __attribute__((ext_vector_type(4))) float f4;

__device__ __forceinline__ float bf2f(unsigned short u) {
    union { unsigned int i; float f; } x; x.i = ((unsigned int)u) << 16; return x.f;
}
__device__ __forceinline__ unsigned short f2bf(float f) {
    __hip_bfloat16 h = __float2bfloat16(f);
    union { __hip_bfloat16 h; unsigned short u; } x; x.h = h; return x.u;
}

__device__ __forceinline__ void g2l16(const unsigned short* g, unsigned short* l) {
    __builtin_amdgcn_global_load_lds(
        (const __attribute__((address_space(1))) unsigned int*)g,
        (__attribute__((address_space(3))) unsigned int*)l,
        16, 0, 0);
}

// ---------------------------------------------------------------------------
// GEMM: y[M,256](bf16) = A[M,K] @ WT[256,K]^T + bias, + BN sums.
// M-tile 64 (1568 blocks -> ~6 blocks/CU capacity, 2x oversubscription),
// BK=64, global_load_lds staging w/ chunk swizzle, XCD-aware block swizzle.
// Wave w: rows wm=(w&1)*32, cols wn=(w>>1)*64; acc 2x4 of 16x16 (32 AGPR).
// ---------------------------------------------------------------------------
template<int K>
__global__ __launch_bounds__(256) void gemm3_k(
    const unsigned short* __restrict__ A,
    const unsigned short* __restrict__ WT,
    const float* __restrict__ bias,
    unsigned short* __restrict__ y,
    float* __restrict__ bns)
{
    const int lin = blockIdx.x;
    const int xcd = lin & 7;
    const int idx = lin >> 3;
    const int row_blk = xcd * RPX64 + (idx >> 1);
    const int nt = idx & 1;
    if (row_blk >= MT64) return;
    const int tile_m = row_blk * 64;
    const int tile_n = nt * 128;

    __shared__ unsigned short As[64 * 64];     // 8 KB
    __shared__ unsigned short Bs[128 * 64];    // 16 KB

    const int w = threadIdx.x >> 6;
    const int l = threadIdx.x & 63;
    const int lm = l & 15;
    const int kq = l >> 4;
    const int wm = (w & 1) << 5;     // 0/32
    const int wn = (w >> 1) << 6;    // 0/64
    const int lrow = l >> 3;
    const int chunk = ((l & 7) + 8 - lrow) & 7;   // swizzle: logical c of row r at phys (c+r)%8

    const unsigned short* srcA[2];
    unsigned short* dstA[2];
#pragma unroll
    for (int i = 0; i < 2; ++i) {
        int rt = w * 16 + i * 8 + lrow;
        int rg = tile_m + rt; if (rg >= M_REAL) rg = M_REAL - 1;
        srcA[i] = A + (size_t)rg * K + chunk * 8;
        dstA[i] = As + (w * 16 + i * 8) * 64;
    }
    const unsigned short* srcB[4];
    unsigned short* dstB[4];
#pragma unroll
    for (int it = 0; it < 4; ++it) {
        int rt = it * 32 + w * 8 + lrow;
        srcB[it] = WT + (size_t)(tile_n + rt) * K + chunk * 8;
        dstB[it] = Bs + (it * 32 + w * 8) * 64;
    }

    unsigned aoff[2], boff[4];
#pragma unroll
    for (int mi = 0; mi < 2; ++mi)
        aoff[mi] = (unsigned)((wm + mi * 16 + lm) * 128 + (((kq + lm) & 7) << 4));
#pragma unroll
    for (int ni = 0; ni < 4; ++ni)
        boff[ni] = (unsigned)((wn + ni * 16 + lm) * 128 + (((kq + lm) & 7) << 4));

    f4 acc[2][4];
#pragma unroll
    for (int mi = 0; mi < 2; ++mi)
#pragma unroll
        for (int ni = 0; ni < 4; ++ni) acc[mi][ni] = (f4){0.f, 0.f, 0.f, 0.f};

    for (int kc = 0; kc < K; kc += 64) {
#pragma unroll
        for (int i = 0; i < 2; ++i) g2l16(srcA[i] + kc, dstA[i]);
#pragma unroll
        for (int it = 0; it < 4; ++it) g2l16(srcB[it] + kc, dstB[it]);
        __syncthreads();
#pragma unroll
        for (int kh = 0; kh < 2; ++kh) {
            const unsigned x = kh << 6;
            short8 af[2], bfr[4];
#pragma unroll
            for (int mi = 0; mi < 2; ++mi)
                af[mi] = *(const short8*)((const char*)As + (aoff[mi] ^ x));
#pragma unroll
            for (int ni = 0; ni < 4; ++ni)
                bfr[ni] = *(const short8*)((const char*)Bs + (boff[ni] ^ x));
#pragma unroll
            for (int mi = 0; mi < 2; ++mi)
#pragma unroll
                for (int ni = 0; ni < 4; ++ni)
                    acc[mi][ni] = __builtin_amdgcn_mfma_f32_16x16x32_bf16(
                        af[mi], bfr[ni], acc[mi][ni], 0, 0, 0);
        }
        __syncthreads();
    }

    int cols[4]; float bv[4];
#pragma unroll
    for (int ni = 0; ni < 4; ++ni) {
        cols[ni] = tile_n + wn + ni * 16 + lm;
        bv[ni] = bias[cols[ni]];
    }
    float s1[4] = {0.f, 0.f, 0.f, 0.f}, s2[4] = {0.f, 0.f, 0.f, 0.f};
#pragma unroll
    for (int mi = 0; mi < 2; ++mi) {
#pragma unroll
        for (int rg = 0; rg < 4; ++rg) {
            int row = tile_m + wm + mi * 16 + kq * 4 + rg;
            if (row < M_REAL) {
                size_t base = (size_t)row * 256;
#pragma unroll
                for (int ni = 0; ni < 4; ++ni) {
                    float v = acc[mi][ni][rg] + bv[ni];
                    y[base + cols[ni]] = f2bf(v);
                    s1[ni] += v; s2[ni] += v * v;
                }
            }
        }
    }
#pragma unroll
    for (int ni = 0; ni < 4; ++ni) {
        float a = s1[ni], b = s2[ni];
        a += __shfl_xor(a, 16); a += __shfl_xor(a, 32);
        b += __shfl_xor(b, 16); b += __shfl_xor(b, 32);
        if (l < 16) {
            atomicAdd(&bns[cols[ni]], a);
            atomicAdd(&bns[256 + cols[ni]], b);
        }
    }
}

// ---------------------------------------------------------------------------
// gather in INPUT space: one wave per dst node; 4-edge unroll.
// buf row (stride S=3D(+64)): [u0 | u1 | x | t-chunk(l0)]
// ---------------------------------------------------------------------------
template<int D, bool HAST>
__global__ __launch_bounds__(256) void gatheru_k(
    unsigned short* buf, const float* __restrict__ comp,
    const unsigned int* __restrict__ rowptr, const float2* __restrict__ erec)
{
    constexpr int E = D / 64;
    constexpr int S = 3 * D + (HAST ? 64 : 0);
    __shared__ float scomp[32];
    if (threadIdx.x < 32) scomp[threadIdx.x] = comp[threadIdx.x];
    __syncthreads();
    int node = blockIdx.x * 4 + (threadIdx.x >> 6);
    int lane = threadIdx.x & 63;
    unsigned int p0 = rowptr[node], p1 = rowptr[node + 1];
    const unsigned short* xbase = buf + 2 * D + lane * E;

    float a0[E], a1[E], b0[E], b1[E];
#pragma unroll
    for (int e = 0; e < E; ++e) { a0[e] = a1[e] = b0[e] = b1[e] = 0.f; }
    float t0 = 0.f, t1 = 0.f;

    unsigned int p = p0;
    for (; p + 4 <= p1; p += 4) {
        float2 r[4];
        unsigned short v[4][E];
#pragma unroll
        for (int j = 0; j < 4; ++j) r[j] = erec[p + j];
#pragma unroll
        for (int j = 0; j < 4; ++j) {
            unsigned q = __float_as_uint(r[j].x);
            const unsigned short* s = xbase + (size_t)(q >> 4) * S;
            if (E == 2) { ushort2 t = *(const ushort2*)s; v[j][0] = t.x; v[j][1] = t.y; }
            else        { ushort4 t = *(const ushort4*)s; v[j][0] = t.x; v[j][1] = t.y;
                          v[j][2] = t.z; v[j][3] = t.w; }
        }
#pragma unroll
        for (int j = 0; j < 4; ++j) {
            unsigned q = __float_as_uint(r[j].x);
            float w0 = scomp[(q & 15) * 2] * r[j].y;
            float w1 = scomp[(q & 15) * 2 + 1] * r[j].y;
            if (HAST) { t0 += w0; t1 += w1; }
            float* d0 = (j & 1) ? b0 : a0;
            float* d1 = (j & 1) ? b1 : a1;
#pragma unroll
            for (int e = 0; e < E; ++e) {
                float xv = bf2f(v[j][e]);
                d0[e] += w0 * xv;
                d1[e] += w1 * xv;
            }
        }
    }
    for (; p < p1; ++p) {
        float2 r = erec[p];
        unsigned q = __float_as_uint(r.x);
        const unsigned short* s = xbase + (size_t)(q >> 4) * S;
        unsigned short v[E];
        if (E == 2) { ushort2 t = *(const ushort2*)s; v[0] = t.x; v[1] = t.y; }
        else        { ushort4 t = *(const ushort4*)s; v[0] = t.x; v[1] = t.y;
                      v[2] = t.z; v[3] = t.w; }
        float w0 = scomp[(q & 15) * 2] * r.y;
        float w1 = scomp[(q & 15) * 2 + 1] * r.y;
        if (HAST) { t0 += w0; t1 += w1; }
#pragma unroll
        for (int e = 0; e < E; ++e) {
            float xv = bf2f(v[e]);
            a0[e] += w0 * xv;
            a1[e] += w1 * xv;
        }
    }

    unsigned short* orow = buf + (size_t)node * S;
    if (E == 2) {
        ushort2 o0, o1;
        o0.x = f2bf(a0[0] + b0[0]); o0.y = f2bf(a0[1] + b0[1]);
        o1.x = f2bf(a1[0] + b1[0]); o1.y = f2bf(a1[1] + b1[1]);
        *(ushort2*)(orow + lane * 2) = o0;
        *(ushort2*)(orow + D + lane * 2) = o1;
    } else {
        ushort4 o0, o1;
        o0.x = f2bf(a0[0] + b0[0]); o0.y = f2bf(a0[1] + b0[1]);
        o0.z = f2bf(a0[2] + b0[2]); o0.w = f2bf(a0[3] + b0[3]);
        o1.x = f2bf(a1[0] + b1[0]); o1.y = f2bf(a1[1] + b1[1]);
        o1.z = f2bf(a1[2] + b1[2]); o1.w = f2bf(a1[3] + b1[3]);
        *(ushort4*)(orow + lane * 4) = o0;
        *(ushort4*)(orow + D + lane * 4) = o1;
    }
    if (HAST) {
        unsigned short tv = (lane == 0) ? f2bf(t0) : (lane == 1) ? f2bf(t1) : (unsigned short)0;
        orow[3 * D + lane] = tv;
    }
}

// row L2-normalize emb -> bf16 x0, into axl0 at col offset 256 (stride 448)
__global__ __launch_bounds__(256) void norm_k(const float* __restrict__ emb,
                                              unsigned short* __restrict__ buf)
{
    int node = blockIdx.x * 4 + (threadIdx.x >> 6);
    int lane = threadIdx.x & 63;
    const float2* p = (const float2*)(emb + (size_t)node * 128);
    float2 v = p[lane];
    float ss = v.x * v.x + v.y * v.y;
#pragma unroll
    for (int o = 32; o > 0; o >>= 1) ss += __shfl_xor(ss, o);
    float inv = 1.f / fmaxf(sqrtf(ss), 1e-12f);
    unsigned short* row = buf + (size_t)node * 448 + 256;
    unsigned int pack = (unsigned int)f2bf(v.x * inv) | ((unsigned int)f2bf(v.y * inv) << 16);
    ((unsigned int*)row)[lane] = pack;
}

__global__ void zero_k(unsigned int* __restrict__ cnt, unsigned int* __restrict__ cntd,
                       unsigned int* __restrict__ cursor, float* __restrict__ bns)
{
    int i = blockIdx.x * 256 + threadIdx.x;
    if (i < 800000) cnt[i] = 0u;
    if (i < 50000) { cntd[i] = 0u; cursor[i] = 0u; }
    if (i < 1536) bns[i] = 0.f;
}

__global__ void cnt_k(const int* __restrict__ ei, const int* __restrict__ et,
                      unsigned int* __restrict__ cnt, unsigned int* __restrict__ cntd)
{
    int e = blockIdx.x * 256 + threadIdx.x;
    if (e >= NEDGE) return;
    int dst = ei[NEDGE + e];
    atomicAdd(&cnt[(size_t)dst * NREL + et[e]], 1u);
    atomicAdd(&cntd[dst], 1u);
}

__global__ __launch_bounds__(SCAN_B) void scan1_k(const unsigned int* __restrict__ cntd,
                                                  unsigned int* __restrict__ partial,
                                                  unsigned int* __restrict__ bsum)
{
    __shared__ unsigned int s[SCAN_B];
    int i = blockIdx.x * SCAN_B + threadIdx.x;
    unsigned int v = (i < NNODES) ? cntd[i] : 0u;
    s[threadIdx.x] = v;
    __syncthreads();
    for (int off = 1; off < SCAN_B; off <<= 1) {
        unsigned int t = (threadIdx.x >= off) ? s[threadIdx.x - off] : 0u;
        __syncthreads();
        s[threadIdx.x] += t;
        __syncthreads();
    }
    if (i < NNODES) partial[i] = s[threadIdx.x];
    if (threadIdx.x == SCAN_B - 1) bsum[blockIdx.x] = s[SCAN_B - 1];
}

__global__ __launch_bounds__(128) void scan2_k(unsigned int* __restrict__ bsum)
{
    __shared__ unsigned int s[128];
    unsigned int v = (threadIdx.x < SCAN_NB) ? bsum[threadIdx.x] : 0u;
    s[threadIdx.x] = v;
    __syncthreads();
    for (int off = 1; off < 128; off <<= 1) {
        unsigned int t = (threadIdx.x >= off) ? s[threadIdx.x - off] : 0u;
        __syncthreads();
        s[threadIdx.x] += t;
        __syncthreads();
    }
    if (threadIdx.x < SCAN_NB) bsum[threadIdx.x] = s[threadIdx.x];
}

__global__ __launch_bounds__(SCAN_B) void scan3_k(const unsigned int* __restrict__ partial,
                                                  const unsigned int* __restrict__ bsum,
                                                  unsigned int* __restrict__ rowptr)
{
    int i = blockIdx.x * SCAN_B + threadIdx.x;
    if (i >= NNODES) return;
    unsigned int off = (blockIdx.x > 0) ? bsum[blockIdx.x - 1] : 0u;
    rowptr[i + 1] = partial[i] + off;
    if (i == 0) rowptr[0] = 0u;
}

__global__ void fill_k(const int* __restrict__ ei, const int* __restrict__ et,
                       const unsigned int* __restrict__ cnt,
                       const unsigned int* __restrict__ rowptr,
                       unsigned int* __restrict__ cursor,
                       float2* __restrict__ erec)
{
    int e = blockIdx.x * 256 + threadIdx.x;
    if (e >= NEDGE) return;
    int dst = ei[NEDGE + e];
    int t = et[e];
    unsigned int c = cnt[(size_t)dst * NREL + t];
    unsigned int pos = rowptr[dst] + atomicAdd(&cursor[dst], 1u);
    float2 r;
    r.x = __uint_as_float(((unsigned)ei[e] << 4) | (unsigned)t);
    r.y = 1.f / (float)(c ? c : 1u);
    erec[pos] = r;
}

__global__ __launch_bounds__(128) void pt_k(const float* __restrict__ proj_w,
                                            float* __restrict__ PT)
{
    int j = blockIdx.x, d = threadIdx.x;
    PT[(size_t)j * 128 + d] = proj_w[(size_t)d * 768 + j];
}

// layer-0 folded weights: wTm0[n][448]: [P@B0 | P@B1 | P@R | pb@B0, pb@B1, 0..]
__global__ __launch_bounds__(128) void pm_k(
    const float* __restrict__ PT, const float* __restrict__ pb,
    const float* __restrict__ b0, const float* __restrict__ r0,
    const float* __restrict__ bias0,
    unsigned short* __restrict__ wTm0, float* __restrict__ biasM0)
{
    __shared__ float sw[128];
    __shared__ float spb[128];
    __shared__ float red[2];
    int seg = blockIdx.x >> 8;
    int n = blockIdx.x & 255;
    int d = threadIdx.x;
    float acc = 0.f, accb = 0.f;
    for (int ch = 0; ch < 6; ++ch) {
        int j0 = ch * 128;
        __syncthreads();
        int j = j0 + d;
        float wv;
        if (seg == 0)      wv = b0[(size_t)j * 256 + n];
        else if (seg == 1) wv = b0[768 * 256 + (size_t)j * 256 + n];
        else               wv = r0[(size_t)j * 256 + n];
        sw[d] = wv;
        spb[d] = pb[j];
        __syncthreads();
#pragma unroll 8
        for (int jj = 0; jj < 128; ++jj)
            acc += PT[(size_t)(j0 + jj) * 128 + d] * sw[jj];
        accb += spb[d] * sw[d];
    }
    for (int o = 32; o > 0; o >>= 1) accb += __shfl_xor(accb, o);
    if ((d & 63) == 0) red[d >> 6] = accb;
    __syncthreads();
    float tb = red[0] + red[1];
    wTm0[(size_t)n * 448 + seg * 128 + d] = f2bf(acc);
    if (seg == 0) { if (d == 0) wTm0[(size_t)n * 448 + 384] = f2bf(tb); }
    else if (seg == 1) { if (d == 0) wTm0[(size_t)n * 448 + 385] = f2bf(tb); }
    else {
        if (d == 0) biasM0[n] = tb + bias0[n];
        if (d >= 2 && d < 64) wTm0[(size_t)n * 448 + 384 + d] = 0;
    }
}

// layers 1/2: wTm[n][768] = [B0 | B1 | R] rows; + biasM fills
__global__ __launch_bounds__(256) void prep_k(
    const float* __restrict__ b1, const float* __restrict__ r1, const float* __restrict__ bias1,
    const float* __restrict__ b2, const float* __restrict__ r2, const float* __restrict__ bias2,
    unsigned short* __restrict__ wTm1, unsigned short* __restrict__ wTm2,
    float* __restrict__ biasM1, float* __restrict__ biasM2)
{
    int b = blockIdx.x;
    int n = threadIdx.x;
    if (b < 1536) {
        int layer = b / 768;
        int rem = b % 768;
        int seg = rem / 256;
        int k = rem % 256;
        const float* bb = layer ? b2 : b1;
        const float* rr = layer ? r2 : r1;
        const float* in = (seg < 2) ? (bb + (size_t)seg * 256 * 256) : rr;
        unsigned short* out = layer ? wTm2 : wTm1;
        out[(size_t)n * 768 + seg * 256 + k] = f2bf(in[(size_t)k * 256 + n]);
    } else {
        int layer = b - 1536;
        float* bm = layer ? biasM2 : biasM1;
        const float* bs = layer ? bias2 : bias1;
        bm[n] = bs[n];
    }
}

__global__ void bnfin_k(const float* __restrict__ bnsum, const float* __restrict__ gamma,
                        const float* __restrict__ beta, float* __restrict__ bnss)
{
    int c = threadIdx.x;
    float mu = bnsum[c] * (1.f / M_REAL);
    float var = bnsum[256 + c] * (1.f / M_REAL) - mu * mu;
    var = fmaxf(var, 0.f);
    float inv = rsqrtf(var + BN_EPS);
    float sc = gamma[c] * inv;
    bnss[c] = sc;
    bnss[256 + c] = beta[c] - mu * sc;
}

// y(bf16) -> BN+relu -> bf16 x into next layer's buf (stride 768, offset 512),
// or f32 d_out for the last layer
template<bool LAST>
__global__ __launch_bounds__(256) void apply_k(const unsigned short* __restrict__ y,
                                               const float* __restrict__ bnss,
                                               unsigned short* __restrict__ xn,
                                               float* __restrict__ outp)
{
    int i = blockIdx.x * 256 + threadIdx.x;
    int row = i >> 6;
    int c4 = (i & 63) * 4;
    ushort4 u = *(const ushort4*)(y + (size_t)row * 256 + c4);
    f4 sc = *(const f4*)(bnss + c4);
    f4 sh = *(const f4*)(bnss + 256 + c4);
    f4 r;
    r.x = fmaxf(bf2f(u.x) * sc.x + sh.x, 0.f);
    r.y = fmaxf(bf2f(u.y) * sc.y + sh.y, 0.f);
    r.z = fmaxf(bf2f(u.z) * sc.z + sh.z, 0.f);
    r.w = fmaxf(bf2f(u.w) * sc.w + sh.w, 0.f);
    if (LAST) {
        *(f4*)(outp + (size_t)row * 256 + c4) = r;
    } else {
        ushort4 o;
        o.x = f2bf(r.x); o.y = f2bf(r.y); o.z = f2bf(r.z); o.w = f2bf(r.w);
        *(ushort4*)(xn + (size_t)row * 768 + 512 + c4) = o;
    }
}

extern "C" void kernel_launch(void* const* d_in, const int* in_sizes, int n_in,
                              void* d_out, int out_size, void* d_ws, size_t ws_size,
                              hipStream_t stream)
{
    const int*   edge_index = (const int*)d_in[0];
    const int*   edge_type  = (const int*)d_in[1];
    const float* emb    = (const float*)d_in[2];
    const float* proj_w = (const float*)d_in[3];
    const float* proj_b = (const float*)d_in[4];
    const float* comp[3]  = {(const float*)d_in[5],  (const float*)d_in[11], (const float*)d_in[17]};
    const float* bases[3] = {(const float*)d_in[6],  (const float*)d_in[12], (const float*)d_in[18]};
    const float* root[3]  = {(const float*)d_in[7],  (const float*)d_in[13], (const float*)d_in[19]};
    const float* biasp[3] = {(const float*)d_in[8],  (const float*)d_in[14], (const float*)d_in[20]};
    const float* gamma[3] = {(const float*)d_in[9],  (const float*)d_in[15], (const float*)d_in[21]};
    const float* beta[3]  = {(const float*)d_in[10], (const float*)d_in[16], (const float*)d_in[22]};

    char* ws = (char*)d_ws;
    size_t off = 0;
    auto alloc = [&](size_t bytes) -> char* {
        char* p = ws + off;
        off = (off + bytes + 255) & ~(size_t)255;
        return p;
    };

    unsigned short* axl0 = (unsigned short*)alloc((size_t)NNODES * 448 * 2);
    unsigned short* axl1 = (unsigned short*)alloc((size_t)NNODES * 768 * 2);
    unsigned short* axl2 = (unsigned short*)alloc((size_t)NNODES * 768 * 2);
    unsigned short* y    = (unsigned short*)alloc((size_t)NNODES * 256 * 2);
    unsigned int*   cnt  = (unsigned int*)alloc((size_t)NNODES * NREL * 4);
    unsigned int*   cntd = (unsigned int*)alloc((size_t)NNODES * 4);
    unsigned int*   rowptr = (unsigned int*)alloc((size_t)(NNODES + 1) * 4);
    unsigned int*   cursor = (unsigned int*)alloc((size_t)NNODES * 4);
    unsigned int*   partial = (unsigned int*)alloc((size_t)NNODES * 4);
    unsigned int*   bsum = (unsigned int*)alloc(128 * 4);
    float2*         erec = (float2*)alloc((size_t)NEDGE * 8);
    float*          PT   = (float*)alloc((size_t)768 * 128 * 4);
    unsigned short* wTm0 = (unsigned short*)alloc((size_t)256 * 448 * 2);
    unsigned short* wTm1 = (unsigned short*)alloc((size_t)256 * 768 * 2);
    unsigned short* wTm2 = (unsigned short*)alloc((size_t)256 * 768 * 2);
    float* biasM = (float*)alloc(3 * 256 * 4);
    float* bns   = (float*)alloc(3 * 512 * 4);
    float* bnss  = (float*)alloc(3 * 512 * 4);

    zero_k<<<3125, 256, 0, stream>>>(cnt, cntd, cursor, bns);
    norm_k<<<NNODES / 4, 256, 0, stream>>>(emb, axl0);
    cnt_k<<<(NEDGE + 255) / 256, 256, 0, stream>>>(edge_index, edge_type, cnt, cntd);
    scan1_k<<<SCAN_NB, SCAN_B, 0, stream>>>(cntd, partial, bsum);
    scan2_k<<<1, 128, 0, stream>>>(bsum);
    scan3_k<<<SCAN_NB, SCAN_B, 0, stream>>>(partial, bsum, rowptr);
    fill_k<<<(NEDGE + 255) / 256, 256, 0, stream>>>(edge_index, edge_type, cnt, rowptr,
                                                    cursor, erec);

    pt_k<<<768, 128, 0, stream>>>(proj_w, PT);
    pm_k<<<768, 128, 0, stream>>>(PT, proj_b, bases[0], root[0], biasp[0], wTm0, biasM);
    prep_k<<<1538, 256, 0, stream>>>(bases[1], root[1], biasp[1],
                                     bases[2], root[2], biasp[2],
                                     wTm1, wTm2, biasM + 256, biasM + 512);

    // ---- layer 0 (D=128, K=448 with t-chunk) ----
    gatheru_k<128, true><<<NNODES / 4, 256, 0, stream>>>(axl0, comp[0], rowptr, erec);
    gemm3_k<448><<<8 * RPX64 * 2, 256, 0, stream>>>(axl0, wTm0, biasM, y, bns);
    bnfin_k<<<1, 256, 0, stream>>>(bns, gamma[0], beta[0], bnss);
    apply_k<false><<<(NNODES * 64) / 256, 256, 0, stream>>>(y, bnss, axl1, nullptr);

    // ---- layer 1 (D=256, K=768) ----
    gatheru_k<256, false><<<NNODES / 4, 256, 0, stream>>>(axl1, comp[1], rowptr, erec);
    gemm3_k<768><<<8 * RPX64 * 2, 256, 0, stream>>>(axl1, wTm1, biasM + 256, y, bns + 512);
    bnfin_k<<<1, 256, 0, stream>>>(bns + 512, gamma[1], beta[1], bnss + 512);
    apply_k<false><<<(NNODES * 64) / 256, 256, 0, stream>>>(y, bnss + 512, axl2, nullptr);

    // ---- layer 2 (D=256, K=768) ----
    gatheru_k<256, false><<<NNODES / 4, 256, 0, stream>>>(axl2, comp[2], rowptr, erec);
    gemm3_k<768><<<8 * RPX64 * 2, 256, 0, stream>>>(axl2, wTm2, biasM + 512, y, bns + 1024);
    bnfin_k<<<1, 256, 0, stream>>>(bns + 1024, gamma[2], beta[2], bnss + 1024);
    apply_k<true><<<(NNODES * 64) / 256, 256, 0, stream>>>(y, bnss + 1024, nullptr, (float*)d_out);
}